// Round 9
// baseline (300.596 us; speedup 1.0000x reference)
//
#include <hip/hip_runtime.h>

// Pipeline (activations NHWC bf16, zero-padded borders, rebuilt every launch):
//  pad_img: images f32 -> imgp [64,260,264,4] bf16 (pad 2, ch3=0)
//  conv1 (MFMA 16x16x32): 3->32 k5 s2 p2 relu -> h1p [64,132,132,32] bf16 (pad 2)
//  conv2 (MFMA 32x32x16, B direct from L2, no LDS/barriers): -> h2p [64,68,68,32] bf16
//  MLP -> per-sample kernels [64,32,25] f32
//  xconv (LDS fp32): depthwise k5 p2 -> sap [64,66,66,32] bf16 (pad 1)
//  mp1 (MFMA 32x32x16, B direct): 32->32 k3 p1 relu -> fp [64,66,66,32] bf16 (pad 1)
//  mp2 (MFMA 16x16x32): 32->2 k3 p1 -> flow f32 (d_out)
// R7 key change: sched_barrier(0) between load-batch and MFMA-chain. R6 proved
// the scheduler sinks loads into the serial MFMA chain (VGPR stayed 32; every
// L2 latency exposed). Also removed conv2's per-kh LDS B-staging + its 10
// __syncthreads per block (B is L2-resident; waves now drift freely).

typedef __attribute__((ext_vector_type(8))) short bf16x8;
typedef __attribute__((ext_vector_type(4))) float f32x4;
typedef __attribute__((ext_vector_type(16))) float f32x16;

__device__ __forceinline__ unsigned short f2bf(float f) {
    unsigned int u = __float_as_uint(f);
    u = (u + 0x7FFFu + ((u >> 16) & 1u)) >> 16;   // RNE
    return (unsigned short)u;
}
__device__ __forceinline__ float bf2f(unsigned short h) {
    return __uint_as_float(((unsigned int)h) << 16);
}

// Zero pad borders of two [64][R][R][32] bf16 tensors (uint view, 16 uints/cell).
__global__ __launch_bounds__(64) void zero_border2(unsigned int* t0, int R0, int p0,
                                                   unsigned int* t1, int R1, int p1) {
    unsigned int* t = blockIdx.y ? t1 : t0;
    const int R = blockIdx.y ? R1 : R0;
    const int pad = blockIdx.y ? p1 : p0;
    const int row = blockIdx.x % R;
    const int n = blockIdx.x / R;
    if (n >= 64) return;
    const int tid = threadIdx.x;
    unsigned int* rp = t + (size_t)(n * R + row) * R * 16;
    if (row < pad || row >= R - pad) {
        for (int i = tid; i < R * 16; i += 64) rp[i] = 0u;
    } else {
        for (int i = tid; i < pad * 16; i += 64) {
            rp[i] = 0u;
            rp[(size_t)(R - pad) * 16 + i] = 0u;
        }
    }
}

// img f32 NHWC -> imgp bf16 [64][260][264][4] (pad 2 each side, ch3 = 0)
__global__ __launch_bounds__(256) void pad_img_kernel(const float* __restrict__ img,
                                                      unsigned short* __restrict__ imgp) {
    const int py = blockIdx.x % 260;
    const int n  = blockIdx.x / 260;
    const int iy = py - 2;
    const bool rowok = (iy >= 0) && (iy < 256);
    const float* srow = img + ((size_t)n * 256 + (rowok ? iy : 0)) * 768;
    unsigned short* drow = imgp + (size_t)(n * 260 + py) * 1056;
    for (int s = threadIdx.x; s < 1056; s += 256) {
        int px = s >> 2, c = s & 3;
        int ix = px - 2;
        float v = 0.f;
        if (rowok && c < 3 && ix >= 0 && ix < 256) v = srow[ix * 3 + c];
        drow[s] = f2bf(v);
    }
}

// All weight repacks in one kernel (ranges documented inline).
__global__ __launch_bounds__(256) void repack_all(const float* __restrict__ pe_w1,
                                                  const float* __restrict__ pe_w2,
                                                  const float* __restrict__ mp_w1,
                                                  const float* __restrict__ mp_w2,
                                                  unsigned short* __restrict__ B1,
                                                  unsigned short* __restrict__ B2,
                                                  unsigned short* __restrict__ Bm1,
                                                  unsigned short* __restrict__ Bm2) {
    int idx = blockIdx.x * 256 + threadIdx.x;
    if (idx < 5120) {          // pe_w1 -> B1 [kh][co][k=32], k=dx*4+c
        int kh = idx / 1024, r = idx % 1024, o = r / 32, k = r % 32, dx = k >> 2, c = k & 3;
        float v = (dx < 5 && c < 3) ? pe_w1[o * 75 + c * 25 + kh * 5 + dx] : 0.f;
        B1[idx] = f2bf(v);
    } else if (idx < 30720) {  // pe_w2 -> B2 [(tap*32+co)*32+ci]
        int i = idx - 5120;
        int co = i / 800, r = i % 800, ci = r / 25, tap = r % 25;
        B2[(tap * 32 + co) * 32 + ci] = f2bf(pe_w2[i]);
    } else if (idx < 39936) {  // mp_w1 -> Bm1 [(tap*32+co)*32+ci]
        int i = idx - 30720;
        int co = i / 288, r = i % 288, ci = r / 9, tap = r % 9;
        Bm1[(tap * 32 + co) * 32 + ci] = f2bf(mp_w1[i]);
    } else if (idx < 44544) {  // mp_w2 -> Bm2 [tap][16co][32ci] (co<2 real)
        int i = idx - 39936;
        int tap = i / 512, r = i % 512, co = r / 32, ci = r % 32;
        float v = (co < 2) ? mp_w2[co * 288 + ci * 9 + tap] : 0.f;
        Bm2[i] = f2bf(v);
    }
}

// Action MLP: actions[64,4] -> relu(256) -> 800; grid (4,64)
__global__ __launch_bounds__(256) void mlp_kernel(const float* __restrict__ actions,
                                                  const float* __restrict__ w1,
                                                  const float* __restrict__ b1,
                                                  const float* __restrict__ w2,
                                                  const float* __restrict__ b2,
                                                  float* __restrict__ aout) {
    int n = blockIdx.y;
    int t = threadIdx.x;
    __shared__ float hid[256];
    float a0 = actions[n * 4 + 0], a1 = actions[n * 4 + 1];
    float a2 = actions[n * 4 + 2], a3 = actions[n * 4 + 3];
    float acc = b1[t];
    acc += a0 * w1[0 * 256 + t] + a1 * w1[1 * 256 + t] +
           a2 * w1[2 * 256 + t] + a3 * w1[3 * 256 + t];
    hid[t] = fmaxf(acc, 0.0f);
    __syncthreads();
    int o = blockIdx.x * 200 + t;
    if (t < 200) {
        float s = b2[o];
        #pragma unroll 4
        for (int i = 0; i < 256; ++i) s += hid[i] * w2[i * 800 + o];
        aout[n * 800 + o] = s;
    }
}

// conv1 MFMA: imgp -> h1p. grid (64,64), block 256. sched_barrier load batching.
__global__ __launch_bounds__(256, 4) void conv1_mfma(const unsigned short* __restrict__ imgp,
                                                     const short* __restrict__ B1,
                                                     const float* __restrict__ bias,
                                                     unsigned short* __restrict__ h1p) {
    const int tid = threadIdx.x;
    const int lane = tid & 63;
    const int w = tid >> 6;
    const int n = blockIdx.y;
    const int cohalf = w & 1;
    const int oy = blockIdx.x * 2 + (w >> 1);     // 0..127
    const int ml = lane & 15;
    const int kg = lane >> 4;

    bf16x8 bfrag[5];
    #pragma unroll
    for (int kh = 0; kh < 5; ++kh)
        bfrag[kh] = *(const bf16x8*)(B1 + ((kh * 32 + cohalf * 16 + ml) * 32 + kg * 8));
    const float bia = bias[cohalf * 16 + ml];
    const int co = cohalf * 16 + ml;

    f32x4 acc[8];
    #pragma unroll
    for (int t = 0; t < 8; ++t) acc[t] = (f32x4){bia, bia, bia, bia};

    #pragma unroll
    for (int kh = 0; kh < 5; ++kh) {
        const unsigned short* rowbase = imgp + (size_t)(n * 260 + 2 * oy + kh) * 1056;
        bf16x8 af[8];
        #pragma unroll
        for (int t = 0; t < 8; ++t) {
            const int px0 = 2 * (16 * t + ml) + 2 * kg;
            af[t] = *(const bf16x8*)(rowbase + px0 * 4);
        }
        __builtin_amdgcn_sched_barrier(0);   // keep all 8 loads issued before MFMAs
        #pragma unroll
        for (int t = 0; t < 8; ++t)
            acc[t] = __builtin_amdgcn_mfma_f32_16x16x32_bf16(af[t], bfrag[kh], acc[t], 0, 0, 0);
    }
    #pragma unroll
    for (int t = 0; t < 8; ++t) {
        #pragma unroll
        for (int r = 0; r < 4; ++r) {
            const int px = 16 * t + kg * 4 + r;
            h1p[((size_t)(n * 132 + oy + 2) * 132 + px + 2) * 32 + co] = f2bf(fmaxf(acc[t][r], 0.f));
        }
    }
}

// conv2 via 32x32x16 MFMA. No LDS, no barriers: B-frags loaded straight from
// global (L2-resident, identical across waves). Per kh: 20 loads batched, then
// sched_barrier(0), then 10 chained MFMAs. grid (32,64), block 256.
__global__ __launch_bounds__(256, 4) void conv2_mfma32(const unsigned short* __restrict__ h1p,
                                                       const unsigned short* __restrict__ B,
                                                       const float* __restrict__ bias,
                                                       unsigned short* __restrict__ h2p) {
    const int tid = threadIdx.x;
    const int lane = tid & 63;
    const int w = tid >> 6;
    const int n = blockIdx.y;
    const int oy = blockIdx.x * 2 + (w >> 1);      // 0..63
    const int x0 = (w & 1) * 32;
    const int co = lane & 31;
    const int kgrp = lane >> 5;                    // 0/1

    const float bia = bias[co];
    f32x16 acc;
    #pragma unroll
    for (int r = 0; r < 16; ++r) acc[r] = bia;

    const unsigned short* bco = B + co * 32 + kgrp * 8;   // + tap*1024
    const int px0 = 2 * (x0 + co);                 // padded x base (stride 2)

    #pragma unroll
    for (int kh = 0; kh < 5; ++kh) {
        const unsigned short* rowbase = h1p + (size_t)(n * 132 + 2 * oy + kh) * (132 * 32) + kgrp * 8;
        bf16x8 a[10], b[10];
        #pragma unroll
        for (int kw = 0; kw < 5; ++kw) {
            const int tap = kh * 5 + kw;
            a[2 * kw]     = *(const bf16x8*)(rowbase + (px0 + kw) * 32);
            a[2 * kw + 1] = *(const bf16x8*)(rowbase + (px0 + kw) * 32 + 16);
            b[2 * kw]     = *(const bf16x8*)(bco + tap * 1024);
            b[2 * kw + 1] = *(const bf16x8*)(bco + tap * 1024 + 16);
        }
        __builtin_amdgcn_sched_barrier(0);   // loads stay above the MFMA chain
        #pragma unroll
        for (int kw = 0; kw < 5; ++kw) {
            acc = __builtin_amdgcn_mfma_f32_32x32x16_bf16(a[2 * kw], b[2 * kw], acc, 0, 0, 0);
            acc = __builtin_amdgcn_mfma_f32_32x32x16_bf16(a[2 * kw + 1], b[2 * kw + 1], acc, 0, 0, 0);
        }
    }
    #pragma unroll
    for (int r = 0; r < 16; ++r) {
        const int px = (r & 3) + 8 * (r >> 2) + 4 * kgrp;
        const int ox = x0 + px;
        h2p[((size_t)(n * 68 + oy + 2) * 68 + ox + 2) * 32 + co] = f2bf(fmaxf(acc[r], 0.f));
    }
}

// xconv: depthwise per-sample k5. Block = (n, 8-row strip); LDS = 12 rows x 68 x 32ci.
__global__ __launch_bounds__(256) void xconv_kernel(const unsigned short* __restrict__ h2p,
                                                    const float* __restrict__ ker,
                                                    unsigned short* __restrict__ sap) {
    __shared__ __align__(16) unsigned short tile[12 * 68 * 32];
    const int tid = threadIdx.x;
    const int n = blockIdx.x;
    const int rb = blockIdx.y;
    const unsigned short* src = h2p + (size_t)(n * 68 + rb * 8) * (68 * 32);
    for (int i = tid; i < 3264; i += 256)
        *(uint4*)(tile + i * 8) = *(const uint4*)(src + i * 8);
    const int ci = tid & 31, xg = tid >> 5;
    const float* kp = ker + (size_t)(n * 32 + ci) * 25;
    float k[25];
    #pragma unroll
    for (int t = 0; t < 25; ++t) k[t] = kp[t];
    __syncthreads();

    float acc[8][8];
    #pragma unroll
    for (int r = 0; r < 8; ++r)
        #pragma unroll
        for (int j = 0; j < 8; ++j) acc[r][j] = 0.f;

    #pragma unroll
    for (int ir = 0; ir < 12; ++ir) {
        float v[12];
        #pragma unroll
        for (int t = 0; t < 12; ++t)
            v[t] = bf2f(tile[(ir * 68 + xg * 8 + t) * 32 + ci]);
        #pragma unroll
        for (int kh = 0; kh < 5; ++kh) {
            const int r = ir - kh;
            if (r >= 0 && r < 8) {
                #pragma unroll
                for (int j = 0; j < 8; ++j) {
                    float s = acc[r][j];
                    #pragma unroll
                    for (int kw = 0; kw < 5; ++kw) s += k[kh * 5 + kw] * v[j + kw];
                    acc[r][j] = s;
                }
            }
        }
    }
    #pragma unroll
    for (int r = 0; r < 8; ++r)
        #pragma unroll
        for (int j = 0; j < 8; ++j)
            sap[((size_t)(n * 66 + rb * 8 + r + 1) * 66 + xg * 8 + j + 1) * 32 + ci] = f2bf(acc[r][j]);
}

// mp1 via 32x32x16 MFMA, B direct from global, sched_barrier batching. grid (32,64).
__global__ __launch_bounds__(256, 4) void mp1_mfma32(const unsigned short* __restrict__ sap,
                                                     const unsigned short* __restrict__ B,
                                                     const float* __restrict__ bias,
                                                     unsigned short* __restrict__ fp) {
    const int tid = threadIdx.x;
    const int lane = tid & 63;
    const int w = tid >> 6;
    const int n = blockIdx.y;
    const int oy = blockIdx.x * 2 + (w >> 1);      // 0..63
    const int x0 = (w & 1) * 32;
    const int co = lane & 31;
    const int kgrp = lane >> 5;

    const float bia = bias[co];
    f32x16 acc;
    #pragma unroll
    for (int r = 0; r < 16; ++r) acc[r] = bia;

    const unsigned short* bco = B + co * 32 + kgrp * 8;
    const int px0 = x0 + co;                       // padded x base (stride 1)

    #pragma unroll
    for (int kh = 0; kh < 3; ++kh) {
        const unsigned short* rowbase = sap + (size_t)(n * 66 + oy + kh) * (66 * 32) + kgrp * 8;
        bf16x8 a[6], b[6];
        #pragma unroll
        for (int kw = 0; kw < 3; ++kw) {
            const int tap = kh * 3 + kw;
            a[2 * kw]     = *(const bf16x8*)(rowbase + (px0 + kw) * 32);
            a[2 * kw + 1] = *(const bf16x8*)(rowbase + (px0 + kw) * 32 + 16);
            b[2 * kw]     = *(const bf16x8*)(bco + tap * 1024);
            b[2 * kw + 1] = *(const bf16x8*)(bco + tap * 1024 + 16);
        }
        __builtin_amdgcn_sched_barrier(0);
        #pragma unroll
        for (int kw = 0; kw < 3; ++kw) {
            acc = __builtin_amdgcn_mfma_f32_32x32x16_bf16(a[2 * kw], b[2 * kw], acc, 0, 0, 0);
            acc = __builtin_amdgcn_mfma_f32_32x32x16_bf16(a[2 * kw + 1], b[2 * kw + 1], acc, 0, 0, 0);
        }
    }
    #pragma unroll
    for (int r = 0; r < 16; ++r) {
        const int px = (r & 3) + 8 * (r >> 2) + 4 * kgrp;
        const int ox = x0 + px;
        fp[((size_t)(n * 66 + oy + 1) * 66 + ox + 1) * 32 + co] = f2bf(fmaxf(acc[r], 0.f));
    }
}

// mp2 MFMA: fp -> flow f32 NCHW. B 16 cols (co 0/1 real). grid (16,64).
__global__ __launch_bounds__(256, 4) void mp2_mfma(const unsigned short* __restrict__ fpb,
                                                   const short* __restrict__ B,
                                                   const float* __restrict__ bias,
                                                   float* __restrict__ out) {
    const int tid = threadIdx.x;
    const int lane = tid & 63;
    const int w = tid >> 6;
    const int n = blockIdx.y;
    const int oy = blockIdx.x * 4 + w;    // 0..63
    const int ml = lane & 15;
    const int kg = lane >> 4;

    bf16x8 bfrag[9];
    #pragma unroll
    for (int t = 0; t < 9; ++t)
        bfrag[t] = *(const bf16x8*)(B + ((t * 16 + ml) * 32 + kg * 8));
    const float bia = (ml < 2) ? bias[ml] : 0.f;

    f32x4 acc[4];
    #pragma unroll
    for (int t = 0; t < 4; ++t) acc[t] = (f32x4){bia, bia, bia, bia};

    #pragma unroll
    for (int kh = 0; kh < 3; ++kh) {
        const unsigned short* rowbase = fpb + (size_t)(n * 66 + oy + kh) * (66 * 32);
        bf16x8 af[12];
        #pragma unroll
        for (int kw = 0; kw < 3; ++kw)
            #pragma unroll
            for (int t = 0; t < 4; ++t)
                af[kw * 4 + t] = *(const bf16x8*)(rowbase + (16 * t + ml + kw) * 32 + kg * 8);
        __builtin_amdgcn_sched_barrier(0);
        #pragma unroll
        for (int kw = 0; kw < 3; ++kw)
            #pragma unroll
            for (int t = 0; t < 4; ++t)
                acc[t] = __builtin_amdgcn_mfma_f32_16x16x32_bf16(af[kw * 4 + t], bfrag[kh * 3 + kw], acc[t], 0, 0, 0);
    }
    if (ml < 2) {
        #pragma unroll
        for (int t = 0; t < 4; ++t) {
            #pragma unroll
            for (int r = 0; r < 4; ++r) {
                const int px = 16 * t + kg * 4 + r;
                out[(size_t)n * 8192 + (size_t)ml * 4096 + (size_t)oy * 64 + px] = acc[t][r];
            }
        }
    }
}

extern "C" void kernel_launch(void* const* d_in, const int* in_sizes, int n_in,
                              void* d_out, int out_size, void* d_ws, size_t ws_size,
                              hipStream_t stream) {
    (void)in_sizes; (void)n_in; (void)out_size; (void)ws_size;
    const float* images  = (const float*)d_in[0];
    const float* actions = (const float*)d_in[1];
    const float* pe_w1   = (const float*)d_in[2];
    const float* pe_b1   = (const float*)d_in[3];
    const float* pe_w2   = (const float*)d_in[4];
    const float* pe_b2   = (const float*)d_in[5];
    const float* ae_w1   = (const float*)d_in[6];
    const float* ae_b1   = (const float*)d_in[7];
    const float* ae_w2   = (const float*)d_in[8];
    const float* ae_b2   = (const float*)d_in[9];
    const float* mp_w1   = (const float*)d_in[10];
    const float* mp_b1   = (const float*)d_in[11];
    const float* mp_w2   = (const float*)d_in[12];
    const float* mp_b2   = (const float*)d_in[13];
    float* out = (float*)d_out;

    char* ws = (char*)d_ws;
    float* a_ker          = (float*)(ws + 0);               // 204800
    unsigned short* B1    = (unsigned short*)(ws + 204800); // 10240
    unsigned short* B2    = (unsigned short*)(ws + 215040); // 51200
    unsigned short* Bm1   = (unsigned short*)(ws + 266240); // 18432
    unsigned short* Bm2   = (unsigned short*)(ws + 284672); // 9216
    unsigned short* h1p   = (unsigned short*)(ws + 524288);    // 71,368,704 -> 71,892,992
    unsigned short* imgp  = (unsigned short*)(ws + 71892992);  // 35,143,680 (dead after conv1)
    unsigned short* h2p   = (unsigned short*)(ws + 71892992);  // 18,939,904 (aliases imgp)
    unsigned short* sap   = (unsigned short*)(ws + 90832896);  // 17,842,176 (aliases imgp tail)
    unsigned short* fpb   = (unsigned short*)(ws + 108675072); // 17,842,176 -> 126,517,248

    repack_all<<<174, 256, 0, stream>>>(pe_w1, pe_w2, mp_w1, mp_w2, B1, B2, Bm1, Bm2);
    mlp_kernel<<<dim3(4, 64), 256, 0, stream>>>(actions, ae_w1, ae_b1, ae_w2, ae_b2, a_ker);
    zero_border2<<<dim3(64 * 132, 2), 64, 0, stream>>>((unsigned int*)h1p, 132, 2,
                                                       (unsigned int*)fpb, 66, 1);

    pad_img_kernel<<<64 * 260, 256, 0, stream>>>(images, imgp);
    conv1_mfma<<<dim3(64, 64), 256, 0, stream>>>(imgp, (const short*)B1, pe_b1, h1p);

    // imgp dead from here; its region is reused by h2p/sap
    zero_border2<<<dim3(64 * 68, 2), 64, 0, stream>>>((unsigned int*)h2p, 68, 2,
                                                      (unsigned int*)sap, 66, 1);

    conv2_mfma32<<<dim3(32, 64), 256, 0, stream>>>(h1p, B2, pe_b2, h2p);
    xconv_kernel<<<dim3(64, 8), 256, 0, stream>>>(h2p, a_ker, sap);
    mp1_mfma32<<<dim3(32, 64), 256, 0, stream>>>(sap, Bm1, mp_b1, fpb);
    mp2_mfma<<<dim3(16, 64), 256, 0, stream>>>(fpb, (const short*)Bm2, mp_b2, out);
}

// Round 10
// 279.540 us; speedup vs baseline: 1.0753x; 1.0753x over previous
//
#include <hip/hip_runtime.h>

// Pipeline (activations NHWC bf16, zero-padded borders, rebuilt every launch):
//  pad_img: images f32 -> imgp [64,260,264,4] bf16 (pad 2, ch3=0)
//  conv1 (MFMA 16x16x32): 3->32 k5 s2 p2 relu -> h1e/h1o [64,132,66,32] bf16
//        (x-PARITY-SPLIT: even/odd padded-x pixels; makes conv2's stride-2
//         gather a stride-1 access. R9 post-mortem: stride-2 A-gather = 128B
//         lane stride, 25% line utilization, was conv2's structural limit.)
//  conv2 (MFMA 32x32x16, B per-kh in LDS, dual acc chains): -> h2p [64,68,68,32]
//  MLP -> per-sample kernels [64,32,25] f32
//  xconv (LDS fp32): depthwise k5 p2 -> sap [64,66,66,32] bf16 (pad 1)
//  mp1 (MFMA 32x32x16, B in LDS once, dual chains): -> fpb [64,66,66,32] bf16
//  mp2 (MFMA 16x16x32): 32->2 k3 p1 -> flow f32 (d_out)
// sched_barrier(0) only after GLOBAL load batches (LDS reads schedule freely).

typedef __attribute__((ext_vector_type(8))) short bf16x8;
typedef __attribute__((ext_vector_type(4))) float f32x4;
typedef __attribute__((ext_vector_type(16))) float f32x16;

__device__ __forceinline__ unsigned short f2bf(float f) {
    unsigned int u = __float_as_uint(f);
    u = (u + 0x7FFFu + ((u >> 16) & 1u)) >> 16;   // RNE
    return (unsigned short)u;
}
__device__ __forceinline__ float bf2f(unsigned short h) {
    return __uint_as_float(((unsigned int)h) << 16);
}

// Zero pad borders of two [64][R][R][32] bf16 tensors (uint view, 16 uints/cell).
__global__ __launch_bounds__(64) void zero_border2(unsigned int* t0, int R0, int p0,
                                                   unsigned int* t1, int R1, int p1) {
    unsigned int* t = blockIdx.y ? t1 : t0;
    const int R = blockIdx.y ? R1 : R0;
    const int pad = blockIdx.y ? p1 : p0;
    const int row = blockIdx.x % R;
    const int n = blockIdx.x / R;
    if (n >= 64) return;
    const int tid = threadIdx.x;
    unsigned int* rp = t + (size_t)(n * R + row) * R * 16;
    if (row < pad || row >= R - pad) {
        for (int i = tid; i < R * 16; i += 64) rp[i] = 0u;
    } else {
        for (int i = tid; i < pad * 16; i += 64) {
            rp[i] = 0u;
            rp[(size_t)(R - pad) * 16 + i] = 0u;
        }
    }
}

// Zero borders of the parity tensors E/O [64][132][66][32]:
// rows {0,1,130,131} fully; cols {0,65} elsewhere. grid (64*132, 2).
__global__ __launch_bounds__(64) void zero_border_eo(unsigned int* E, unsigned int* O) {
    unsigned int* t = blockIdx.y ? O : E;
    const int row = blockIdx.x % 132;
    const int n = blockIdx.x / 132;
    const int tid = threadIdx.x;
    unsigned int* rp = t + (size_t)(n * 132 + row) * (66 * 16);
    if (row < 2 || row >= 130) {
        for (int i = tid; i < 66 * 16; i += 64) rp[i] = 0u;
    } else if (tid < 16) {
        rp[tid] = 0u;
        rp[65 * 16 + tid] = 0u;
    }
}

// img f32 NHWC -> imgp bf16 [64][260][264][4] (pad 2 each side, ch3 = 0)
__global__ __launch_bounds__(256) void pad_img_kernel(const float* __restrict__ img,
                                                      unsigned short* __restrict__ imgp) {
    const int py = blockIdx.x % 260;
    const int n  = blockIdx.x / 260;
    const int iy = py - 2;
    const bool rowok = (iy >= 0) && (iy < 256);
    const float* srow = img + ((size_t)n * 256 + (rowok ? iy : 0)) * 768;
    unsigned short* drow = imgp + (size_t)(n * 260 + py) * 1056;
    for (int s = threadIdx.x; s < 1056; s += 256) {
        int px = s >> 2, c = s & 3;
        int ix = px - 2;
        float v = 0.f;
        if (rowok && c < 3 && ix >= 0 && ix < 256) v = srow[ix * 3 + c];
        drow[s] = f2bf(v);
    }
}

// All weight repacks in one kernel (ranges documented inline).
__global__ __launch_bounds__(256) void repack_all(const float* __restrict__ pe_w1,
                                                  const float* __restrict__ pe_w2,
                                                  const float* __restrict__ mp_w1,
                                                  const float* __restrict__ mp_w2,
                                                  unsigned short* __restrict__ B1,
                                                  unsigned short* __restrict__ B2,
                                                  unsigned short* __restrict__ Bm1,
                                                  unsigned short* __restrict__ Bm2) {
    int idx = blockIdx.x * 256 + threadIdx.x;
    if (idx < 5120) {          // pe_w1 -> B1 [kh][co][k=32], k=dx*4+c
        int kh = idx / 1024, r = idx % 1024, o = r / 32, k = r % 32, dx = k >> 2, c = k & 3;
        float v = (dx < 5 && c < 3) ? pe_w1[o * 75 + c * 25 + kh * 5 + dx] : 0.f;
        B1[idx] = f2bf(v);
    } else if (idx < 30720) {  // pe_w2 -> B2 [(tap*32+co)*32+ci]
        int i = idx - 5120;
        int co = i / 800, r = i % 800, ci = r / 25, tap = r % 25;
        B2[(tap * 32 + co) * 32 + ci] = f2bf(pe_w2[i]);
    } else if (idx < 39936) {  // mp_w1 -> Bm1 [(tap*32+co)*32+ci]
        int i = idx - 30720;
        int co = i / 288, r = i % 288, ci = r / 9, tap = r % 9;
        Bm1[(tap * 32 + co) * 32 + ci] = f2bf(mp_w1[i]);
    } else if (idx < 44544) {  // mp_w2 -> Bm2 [tap][16co][32ci] (co<2 real)
        int i = idx - 39936;
        int tap = i / 512, r = i % 512, co = r / 32, ci = r % 32;
        float v = (co < 2) ? mp_w2[co * 288 + ci * 9 + tap] : 0.f;
        Bm2[i] = f2bf(v);
    }
}

// Action MLP: actions[64,4] -> relu(256) -> 800; grid (4,64)
__global__ __launch_bounds__(256) void mlp_kernel(const float* __restrict__ actions,
                                                  const float* __restrict__ w1,
                                                  const float* __restrict__ b1,
                                                  const float* __restrict__ w2,
                                                  const float* __restrict__ b2,
                                                  float* __restrict__ aout) {
    int n = blockIdx.y;
    int t = threadIdx.x;
    __shared__ float hid[256];
    float a0 = actions[n * 4 + 0], a1 = actions[n * 4 + 1];
    float a2 = actions[n * 4 + 2], a3 = actions[n * 4 + 3];
    float acc = b1[t];
    acc += a0 * w1[0 * 256 + t] + a1 * w1[1 * 256 + t] +
           a2 * w1[2 * 256 + t] + a3 * w1[3 * 256 + t];
    hid[t] = fmaxf(acc, 0.0f);
    __syncthreads();
    int o = blockIdx.x * 200 + t;
    if (t < 200) {
        float s = b2[o];
        #pragma unroll 4
        for (int i = 0; i < 256; ++i) s += hid[i] * w2[i * 800 + o];
        aout[n * 800 + o] = s;
    }
}

// conv1 MFMA: imgp -> h1e/h1o (parity split). grid (64,64), block 256.
__global__ __launch_bounds__(256, 4) void conv1_mfma(const unsigned short* __restrict__ imgp,
                                                     const short* __restrict__ B1,
                                                     const float* __restrict__ bias,
                                                     unsigned short* __restrict__ h1e,
                                                     unsigned short* __restrict__ h1o) {
    const int tid = threadIdx.x;
    const int lane = tid & 63;
    const int w = tid >> 6;
    const int n = blockIdx.y;
    const int cohalf = w & 1;
    const int oy = blockIdx.x * 2 + (w >> 1);     // 0..127
    const int ml = lane & 15;
    const int kg = lane >> 4;

    bf16x8 bfrag[5];
    #pragma unroll
    for (int kh = 0; kh < 5; ++kh)
        bfrag[kh] = *(const bf16x8*)(B1 + ((kh * 32 + cohalf * 16 + ml) * 32 + kg * 8));
    const float bia = bias[cohalf * 16 + ml];
    const int co = cohalf * 16 + ml;

    f32x4 acc[8];
    #pragma unroll
    for (int t = 0; t < 8; ++t) acc[t] = (f32x4){bia, bia, bia, bia};

    #pragma unroll
    for (int kh = 0; kh < 5; ++kh) {
        const unsigned short* rowbase = imgp + (size_t)(n * 260 + 2 * oy + kh) * 1056;
        bf16x8 af[8];
        #pragma unroll
        for (int t = 0; t < 8; ++t) {
            const int px0 = 2 * (16 * t + ml) + 2 * kg;
            af[t] = *(const bf16x8*)(rowbase + px0 * 4);
        }
        __builtin_amdgcn_sched_barrier(0);
        #pragma unroll
        for (int t = 0; t < 8; ++t)
            acc[t] = __builtin_amdgcn_mfma_f32_16x16x32_bf16(af[t], bfrag[kh], acc[t], 0, 0, 0);
    }
    // store into parity tensors: padded p = px+2; even p -> E[p>>1], odd -> O[(p-1)>>1]
    const size_t rowoff = ((size_t)(n * 132) + oy + 2) * 2112 + co;   // 2112 = 66*32
    #pragma unroll
    for (int t = 0; t < 8; ++t) {
        #pragma unroll
        for (int r = 0; r < 4; ++r) {
            const int px = 16 * t + kg * 4 + r;
            const unsigned short v = f2bf(fmaxf(acc[t][r], 0.f));
            if ((r & 1) == 0) h1e[rowoff + (size_t)((px + 2) >> 1) * 32] = v;
            else              h1o[rowoff + (size_t)((px + 1) >> 1) * 32] = v;
        }
    }
}

// conv2 via 32x32x16 MFMA on parity-split input (all A-loads stride-1).
// B staged per-kh in LDS (rows padded to 40 shorts). Dual acc chains (even/odd
// taps) halve the dependent-MFMA latency chain. grid (32,64), block 256.
__global__ __launch_bounds__(256, 4) void conv2_mfma32(const unsigned short* __restrict__ h1e,
                                                       const unsigned short* __restrict__ h1o,
                                                       const unsigned int* __restrict__ B,
                                                       const float* __restrict__ bias,
                                                       unsigned short* __restrict__ h2p) {
    __shared__ unsigned int Bs[5 * 32 * 20];       // 5 taps x 32 co x 40 bf16 = 12800 B
    const int tid = threadIdx.x;
    const int lane = tid & 63;
    const int w = tid >> 6;
    const int n = blockIdx.y;
    const int oy = blockIdx.x * 2 + (w >> 1);      // 0..63
    const int x0 = (w & 1) * 32;
    const int ml = lane & 31;                      // A-row (pixel) and B-col (co)
    const int kgrp = lane >> 5;                    // 0/1

    const float bia = bias[ml];
    f32x16 accA, accB;
    #pragma unroll
    for (int r = 0; r < 16; ++r) { accA[r] = bia; accB[r] = 0.f; }

    const unsigned short* bbase = (const unsigned short*)Bs + ml * 40 + kgrp * 8;
    const int qbase = (x0 + ml) * 32 + kgrp * 8;   // stride-1 pixel index in E/O

    for (int kh = 0; kh < 5; ++kh) {
        if (kh) __syncthreads();
        const unsigned int* src = B + kh * 2560;
        #pragma unroll
        for (int i = tid; i < 2560; i += 256) {
            int row = i >> 4, p = i & 15;
            Bs[row * 20 + p] = src[i];
        }
        __syncthreads();

        const size_t rowoff = ((size_t)(n * 132) + 2 * oy + kh) * 2112;
        const unsigned short* re = h1e + rowoff + qbase;
        const unsigned short* ro = h1o + rowoff + qbase;
        bf16x8 ae[6], ao[4];
        #pragma unroll
        for (int j = 0; j < 3; ++j) {
            ae[2 * j]     = *(const bf16x8*)(re + j * 32);
            ae[2 * j + 1] = *(const bf16x8*)(re + j * 32 + 16);
        }
        #pragma unroll
        for (int j = 0; j < 2; ++j) {
            ao[2 * j]     = *(const bf16x8*)(ro + j * 32);
            ao[2 * j + 1] = *(const bf16x8*)(ro + j * 32 + 16);
        }
        __builtin_amdgcn_sched_barrier(0);   // global A-loads stay batched above
        // taps: kw=0,2,4 -> chain A (even pixels); kw=1,3 -> chain B (odd)
        #pragma unroll
        for (int j = 0; j < 3; ++j) {        // kw = 2j
            const bf16x8 b0 = *(const bf16x8*)(bbase + (2 * j) * 1280);
            const bf16x8 b1 = *(const bf16x8*)(bbase + (2 * j) * 1280 + 16);
            accA = __builtin_amdgcn_mfma_f32_32x32x16_bf16(ae[2 * j], b0, accA, 0, 0, 0);
            accA = __builtin_amdgcn_mfma_f32_32x32x16_bf16(ae[2 * j + 1], b1, accA, 0, 0, 0);
        }
        #pragma unroll
        for (int j = 0; j < 2; ++j) {        // kw = 2j+1
            const bf16x8 b0 = *(const bf16x8*)(bbase + (2 * j + 1) * 1280);
            const bf16x8 b1 = *(const bf16x8*)(bbase + (2 * j + 1) * 1280 + 16);
            accB = __builtin_amdgcn_mfma_f32_32x32x16_bf16(ao[2 * j], b0, accB, 0, 0, 0);
            accB = __builtin_amdgcn_mfma_f32_32x32x16_bf16(ao[2 * j + 1], b1, accB, 0, 0, 0);
        }
    }
    #pragma unroll
    for (int r = 0; r < 16; ++r) {
        const int px = (r & 3) + 8 * (r >> 2) + 4 * kgrp;
        const int ox = x0 + px;
        h2p[((size_t)(n * 68 + oy + 2) * 68 + ox + 2) * 32 + ml] =
            f2bf(fmaxf(accA[r] + accB[r], 0.f));
    }
}

// xconv: depthwise per-sample k5. Block = (n, 8-row strip); LDS = 12 rows x 68 x 32ci.
__global__ __launch_bounds__(256) void xconv_kernel(const unsigned short* __restrict__ h2p,
                                                    const float* __restrict__ ker,
                                                    unsigned short* __restrict__ sap) {
    __shared__ __align__(16) unsigned short tile[12 * 68 * 32];
    const int tid = threadIdx.x;
    const int n = blockIdx.x;
    const int rb = blockIdx.y;
    const unsigned short* src = h2p + (size_t)(n * 68 + rb * 8) * (68 * 32);
    for (int i = tid; i < 3264; i += 256)
        *(uint4*)(tile + i * 8) = *(const uint4*)(src + i * 8);
    const int ci = tid & 31, xg = tid >> 5;
    const float* kp = ker + (size_t)(n * 32 + ci) * 25;
    float k[25];
    #pragma unroll
    for (int t = 0; t < 25; ++t) k[t] = kp[t];
    __syncthreads();

    float acc[8][8];
    #pragma unroll
    for (int r = 0; r < 8; ++r)
        #pragma unroll
        for (int j = 0; j < 8; ++j) acc[r][j] = 0.f;

    #pragma unroll
    for (int ir = 0; ir < 12; ++ir) {
        float v[12];
        #pragma unroll
        for (int t = 0; t < 12; ++t)
            v[t] = bf2f(tile[(ir * 68 + xg * 8 + t) * 32 + ci]);
        #pragma unroll
        for (int kh = 0; kh < 5; ++kh) {
            const int r = ir - kh;
            if (r >= 0 && r < 8) {
                #pragma unroll
                for (int j = 0; j < 8; ++j) {
                    float s = acc[r][j];
                    #pragma unroll
                    for (int kw = 0; kw < 5; ++kw) s += k[kh * 5 + kw] * v[j + kw];
                    acc[r][j] = s;
                }
            }
        }
    }
    #pragma unroll
    for (int r = 0; r < 8; ++r)
        #pragma unroll
        for (int j = 0; j < 8; ++j)
            sap[((size_t)(n * 66 + rb * 8 + r + 1) * 66 + xg * 8 + j + 1) * 32 + ci] = f2bf(acc[r][j]);
}

// mp1 via 32x32x16 MFMA; all 9 taps staged once in LDS; dual acc chains by tap
// parity. grid (32,64), block 256.
__global__ __launch_bounds__(256, 4) void mp1_mfma32(const unsigned short* __restrict__ sap,
                                                     const unsigned int* __restrict__ B,
                                                     const float* __restrict__ bias,
                                                     unsigned short* __restrict__ fp) {
    __shared__ unsigned int Bs[9 * 32 * 20];       // 23040 B
    const int tid = threadIdx.x;
    #pragma unroll
    for (int i = tid; i < 4608; i += 256) {
        int row = i >> 4, p = i & 15;
        Bs[row * 20 + p] = B[i];
    }
    __syncthreads();

    const int lane = tid & 63;
    const int w = tid >> 6;
    const int n = blockIdx.y;
    const int oy = blockIdx.x * 2 + (w >> 1);      // 0..63
    const int x0 = (w & 1) * 32;
    const int ml = lane & 31;
    const int kgrp = lane >> 5;

    const float bia = bias[ml];
    f32x16 accA, accB;
    #pragma unroll
    for (int r = 0; r < 16; ++r) { accA[r] = bia; accB[r] = 0.f; }

    const unsigned short* bbase = (const unsigned short*)Bs + ml * 40 + kgrp * 8;
    const int px0 = x0 + ml;

    #pragma unroll
    for (int kh = 0; kh < 3; ++kh) {
        const unsigned short* rowbase = sap + (size_t)(n * 66 + oy + kh) * 2112 + kgrp * 8;
        bf16x8 a[6];
        #pragma unroll
        for (int kw = 0; kw < 3; ++kw) {
            a[2 * kw]     = *(const bf16x8*)(rowbase + (px0 + kw) * 32);
            a[2 * kw + 1] = *(const bf16x8*)(rowbase + (px0 + kw) * 32 + 16);
        }
        __builtin_amdgcn_sched_barrier(0);
        #pragma unroll
        for (int kw = 0; kw < 3; ++kw) {
            const int tap = kh * 3 + kw;
            const bf16x8 b0 = *(const bf16x8*)(bbase + tap * 1280);
            const bf16x8 b1 = *(const bf16x8*)(bbase + tap * 1280 + 16);
            if (tap & 1) {
                accB = __builtin_amdgcn_mfma_f32_32x32x16_bf16(a[2 * kw], b0, accB, 0, 0, 0);
                accB = __builtin_amdgcn_mfma_f32_32x32x16_bf16(a[2 * kw + 1], b1, accB, 0, 0, 0);
            } else {
                accA = __builtin_amdgcn_mfma_f32_32x32x16_bf16(a[2 * kw], b0, accA, 0, 0, 0);
                accA = __builtin_amdgcn_mfma_f32_32x32x16_bf16(a[2 * kw + 1], b1, accA, 0, 0, 0);
            }
        }
    }
    #pragma unroll
    for (int r = 0; r < 16; ++r) {
        const int px = (r & 3) + 8 * (r >> 2) + 4 * kgrp;
        const int ox = x0 + px;
        fp[((size_t)(n * 66 + oy + 1) * 66 + ox + 1) * 32 + ml] =
            f2bf(fmaxf(accA[r] + accB[r], 0.f));
    }
}

// mp2 MFMA: fpb -> flow f32 NCHW. B 16 cols (co 0/1 real). grid (16,64).
__global__ __launch_bounds__(256, 4) void mp2_mfma(const unsigned short* __restrict__ fpb,
                                                   const short* __restrict__ B,
                                                   const float* __restrict__ bias,
                                                   float* __restrict__ out) {
    const int tid = threadIdx.x;
    const int lane = tid & 63;
    const int w = tid >> 6;
    const int n = blockIdx.y;
    const int oy = blockIdx.x * 4 + w;    // 0..63
    const int ml = lane & 15;
    const int kg = lane >> 4;

    bf16x8 bfrag[9];
    #pragma unroll
    for (int t = 0; t < 9; ++t)
        bfrag[t] = *(const bf16x8*)(B + ((t * 16 + ml) * 32 + kg * 8));
    const float bia = (ml < 2) ? bias[ml] : 0.f;

    f32x4 acc[4];
    #pragma unroll
    for (int t = 0; t < 4; ++t) acc[t] = (f32x4){bia, bia, bia, bia};

    #pragma unroll
    for (int kh = 0; kh < 3; ++kh) {
        const unsigned short* rowbase = fpb + (size_t)(n * 66 + oy + kh) * (66 * 32);
        bf16x8 af[12];
        #pragma unroll
        for (int kw = 0; kw < 3; ++kw)
            #pragma unroll
            for (int t = 0; t < 4; ++t)
                af[kw * 4 + t] = *(const bf16x8*)(rowbase + (16 * t + ml + kw) * 32 + kg * 8);
        __builtin_amdgcn_sched_barrier(0);
        #pragma unroll
        for (int kw = 0; kw < 3; ++kw)
            #pragma unroll
            for (int t = 0; t < 4; ++t)
                acc[t] = __builtin_amdgcn_mfma_f32_16x16x32_bf16(af[kw * 4 + t], bfrag[kh * 3 + kw], acc[t], 0, 0, 0);
    }
    if (ml < 2) {
        #pragma unroll
        for (int t = 0; t < 4; ++t) {
            #pragma unroll
            for (int r = 0; r < 4; ++r) {
                const int px = 16 * t + kg * 4 + r;
                out[(size_t)n * 8192 + (size_t)ml * 4096 + (size_t)oy * 64 + px] = acc[t][r];
            }
        }
    }
}

extern "C" void kernel_launch(void* const* d_in, const int* in_sizes, int n_in,
                              void* d_out, int out_size, void* d_ws, size_t ws_size,
                              hipStream_t stream) {
    (void)in_sizes; (void)n_in; (void)out_size; (void)ws_size;
    const float* images  = (const float*)d_in[0];
    const float* actions = (const float*)d_in[1];
    const float* pe_w1   = (const float*)d_in[2];
    const float* pe_b1   = (const float*)d_in[3];
    const float* pe_w2   = (const float*)d_in[4];
    const float* pe_b2   = (const float*)d_in[5];
    const float* ae_w1   = (const float*)d_in[6];
    const float* ae_b1   = (const float*)d_in[7];
    const float* ae_w2   = (const float*)d_in[8];
    const float* ae_b2   = (const float*)d_in[9];
    const float* mp_w1   = (const float*)d_in[10];
    const float* mp_b1   = (const float*)d_in[11];
    const float* mp_w2   = (const float*)d_in[12];
    const float* mp_b2   = (const float*)d_in[13];
    float* out = (float*)d_out;

    char* ws = (char*)d_ws;
    float* a_ker          = (float*)(ws + 0);               // 204800
    unsigned short* B1    = (unsigned short*)(ws + 204800); // 10240
    unsigned short* B2    = (unsigned short*)(ws + 215040); // 51200
    unsigned short* Bm1   = (unsigned short*)(ws + 266240); // 18432
    unsigned short* Bm2   = (unsigned short*)(ws + 284672); // 9216
    unsigned short* h1e   = (unsigned short*)(ws + 524288);    // 64*132*66*32*2 = 35,684,352
    unsigned short* h1o   = (unsigned short*)(ws + 36208640);  // 35,684,352 -> 71,892,992
    unsigned short* imgp  = (unsigned short*)(ws + 71892992);  // 35,143,680 (dead after conv1)
    unsigned short* h2p   = (unsigned short*)(ws + 71892992);  // 18,939,904 (aliases imgp)
    unsigned short* sap   = (unsigned short*)(ws + 90832896);  // 17,842,176 (aliases imgp tail)
    unsigned short* fpb   = (unsigned short*)(ws + 108675072); // 17,842,176 -> 126,517,248

    repack_all<<<174, 256, 0, stream>>>(pe_w1, pe_w2, mp_w1, mp_w2, B1, B2, Bm1, Bm2);
    mlp_kernel<<<dim3(4, 64), 256, 0, stream>>>(actions, ae_w1, ae_b1, ae_w2, ae_b2, a_ker);
    zero_border_eo<<<dim3(64 * 132, 2), 64, 0, stream>>>((unsigned int*)h1e, (unsigned int*)h1o);
    zero_border2<<<dim3(64 * 66, 1), 64, 0, stream>>>((unsigned int*)fpb, 66, 1,
                                                      (unsigned int*)fpb, 66, 1);

    pad_img_kernel<<<64 * 260, 256, 0, stream>>>(images, imgp);
    conv1_mfma<<<dim3(64, 64), 256, 0, stream>>>(imgp, (const short*)B1, pe_b1, h1e, h1o);

    // imgp dead from here; its region is reused by h2p/sap
    zero_border2<<<dim3(64 * 68, 2), 64, 0, stream>>>((unsigned int*)h2p, 68, 2,
                                                      (unsigned int*)sap, 66, 1);

    conv2_mfma32<<<dim3(32, 64), 256, 0, stream>>>(h1e, h1o, (const unsigned int*)B2, pe_b2, h2p);
    xconv_kernel<<<dim3(64, 8), 256, 0, stream>>>(h2p, a_ker, sap);
    mp1_mfma32<<<dim3(32, 64), 256, 0, stream>>>(sap, (const unsigned int*)Bm1, mp_b1, fpb);
    mp2_mfma<<<dim3(16, 64), 256, 0, stream>>>(fpb, (const short*)Bm2, mp_b2, out);
}

// Round 12
// 276.990 us; speedup vs baseline: 1.0852x; 1.0092x over previous
//
#include <hip/hip_runtime.h>

// Pipeline (activations NHWC bf16, zero-padded borders, rebuilt every launch):
//  pad_img: images f32 -> imgp [64,260,264,4] bf16 (pad 2, ch3=0), 8B stores
//  conv1 (MFMA 16x16x32, SWAPPED operands -> lane holds 4 consecutive co of one
//         pixel -> uint2 stores): 3->32 k5 s2 p2 relu -> h1e/h1o [64,132,66,32]
//  conv2 (MFMA 32x32x16, parity-split stride-1 A, B per-kh LDS, dual chains,
//         SWAPPED operands -> 4x uint2 stores): -> h2p [64,68,68,32]
//  MLP -> per-sample kernels [64,32,25] f32
//  xconv (LDS fp32, LDS-transpose epilogue -> coalesced 16B stores): -> sap
//  mp1 (MFMA 32x32x16, SWAPPED): -> fpb [64,66,66,32]
//  mp2 (MFMA 16x16x32): 32->2 k3 p1 -> flow f32 (d_out)
// R11 key change: kill scalar 2B bf16 stores everywhere (G13). Operand swap is
// data-free: lane l's A[m=l&31][k] fragment == B[k][n=l&31] fragment, so only
// intrinsic arg order + bias (moved to epilogue as f32x4) + store loop change.

typedef __attribute__((ext_vector_type(8))) short bf16x8;
typedef __attribute__((ext_vector_type(4))) float f32x4;
typedef __attribute__((ext_vector_type(16))) float f32x16;

__device__ __forceinline__ unsigned short f2bf(float f) {
    unsigned int u = __float_as_uint(f);
    u = (u + 0x7FFFu + ((u >> 16) & 1u)) >> 16;   // RNE
    return (unsigned short)u;
}
__device__ __forceinline__ unsigned int pk2(float lo, float hi) {
    return (unsigned int)f2bf(lo) | ((unsigned int)f2bf(hi) << 16);
}
__device__ __forceinline__ float bf2f(unsigned short h) {
    return __uint_as_float(((unsigned int)h) << 16);
}

// Zero pad borders of two [64][R][R][32] bf16 tensors (uint view, 16 uints/cell).
__global__ __launch_bounds__(64) void zero_border2(unsigned int* t0, int R0, int p0,
                                                   unsigned int* t1, int R1, int p1) {
    unsigned int* t = blockIdx.y ? t1 : t0;
    const int R = blockIdx.y ? R1 : R0;
    const int pad = blockIdx.y ? p1 : p0;
    const int row = blockIdx.x % R;
    const int n = blockIdx.x / R;
    if (n >= 64) return;
    const int tid = threadIdx.x;
    unsigned int* rp = t + (size_t)(n * R + row) * R * 16;
    if (row < pad || row >= R - pad) {
        for (int i = tid; i < R * 16; i += 64) rp[i] = 0u;
    } else {
        for (int i = tid; i < pad * 16; i += 64) {
            rp[i] = 0u;
            rp[(size_t)(R - pad) * 16 + i] = 0u;
        }
    }
}

// Zero borders of parity tensors E/O [64][132][66][32]. grid (64*132, 2).
__global__ __launch_bounds__(64) void zero_border_eo(unsigned int* E, unsigned int* O) {
    unsigned int* t = blockIdx.y ? O : E;
    const int row = blockIdx.x % 132;
    const int n = blockIdx.x / 132;
    const int tid = threadIdx.x;
    unsigned int* rp = t + (size_t)(n * 132 + row) * (66 * 16);
    if (row < 2 || row >= 130) {
        for (int i = tid; i < 66 * 16; i += 64) rp[i] = 0u;
    } else if (tid < 16) {
        rp[tid] = 0u;
        rp[65 * 16 + tid] = 0u;
    }
}

// img f32 NHWC -> imgp bf16 [64][260][264][4]; one pixel/thread, 8B stores.
__global__ __launch_bounds__(256) void pad_img_kernel(const float* __restrict__ img,
                                                      unsigned short* __restrict__ imgp) {
    const int py = blockIdx.x % 260;
    const int n  = blockIdx.x / 260;
    const int iy = py - 2;
    const bool rowok = (iy >= 0) && (iy < 256);
    const float* srow = img + ((size_t)n * 256 + (rowok ? iy : 0)) * 768;
    unsigned short* drow = imgp + (size_t)(n * 260 + py) * 1056;
    for (int px = threadIdx.x; px < 264; px += 256) {
        const int ix = px - 2;
        float c0 = 0.f, c1 = 0.f, c2 = 0.f;
        if (rowok && ix >= 0 && ix < 256) {
            c0 = srow[ix * 3 + 0]; c1 = srow[ix * 3 + 1]; c2 = srow[ix * 3 + 2];
        }
        uint2 u; u.x = pk2(c0, c1); u.y = pk2(c2, 0.f);
        *(uint2*)(drow + px * 4) = u;
    }
}

// All weight repacks in one kernel (ranges documented inline).
__global__ __launch_bounds__(256) void repack_all(const float* __restrict__ pe_w1,
                                                  const float* __restrict__ pe_w2,
                                                  const float* __restrict__ mp_w1,
                                                  const float* __restrict__ mp_w2,
                                                  unsigned short* __restrict__ B1,
                                                  unsigned short* __restrict__ B2,
                                                  unsigned short* __restrict__ Bm1,
                                                  unsigned short* __restrict__ Bm2) {
    int idx = blockIdx.x * 256 + threadIdx.x;
    if (idx < 5120) {          // pe_w1 -> B1 [kh][co][k=32], k=dx*4+c
        int kh = idx / 1024, r = idx % 1024, o = r / 32, k = r % 32, dx = k >> 2, c = k & 3;
        float v = (dx < 5 && c < 3) ? pe_w1[o * 75 + c * 25 + kh * 5 + dx] : 0.f;
        B1[idx] = f2bf(v);
    } else if (idx < 30720) {  // pe_w2 -> B2 [(tap*32+co)*32+ci]
        int i = idx - 5120;
        int co = i / 800, r = i % 800, ci = r / 25, tap = r % 25;
        B2[(tap * 32 + co) * 32 + ci] = f2bf(pe_w2[i]);
    } else if (idx < 39936) {  // mp_w1 -> Bm1 [(tap*32+co)*32+ci]
        int i = idx - 30720;
        int co = i / 288, r = i % 288, ci = r / 9, tap = r % 9;
        Bm1[(tap * 32 + co) * 32 + ci] = f2bf(mp_w1[i]);
    } else if (idx < 44544) {  // mp_w2 -> Bm2 [tap][16co][32ci] (co<2 real)
        int i = idx - 39936;
        int tap = i / 512, r = i % 512, co = r / 32, ci = r % 32;
        float v = (co < 2) ? mp_w2[co * 288 + ci * 9 + tap] : 0.f;
        Bm2[i] = f2bf(v);
    }
}

// Action MLP: actions[64,4] -> relu(256) -> 800; grid (4,64)
__global__ __launch_bounds__(256) void mlp_kernel(const float* __restrict__ actions,
                                                  const float* __restrict__ w1,
                                                  const float* __restrict__ b1,
                                                  const float* __restrict__ w2,
                                                  const float* __restrict__ b2,
                                                  float* __restrict__ aout) {
    int n = blockIdx.y;
    int t = threadIdx.x;
    __shared__ float hid[256];
    float a0 = actions[n * 4 + 0], a1 = actions[n * 4 + 1];
    float a2 = actions[n * 4 + 2], a3 = actions[n * 4 + 3];
    float acc = b1[t];
    acc += a0 * w1[0 * 256 + t] + a1 * w1[1 * 256 + t] +
           a2 * w1[2 * 256 + t] + a3 * w1[3 * 256 + t];
    hid[t] = fmaxf(acc, 0.0f);
    __syncthreads();
    int o = blockIdx.x * 200 + t;
    if (t < 200) {
        float s = b2[o];
        #pragma unroll 4
        for (int i = 0; i < 256; ++i) s += hid[i] * w2[i * 800 + o];
        aout[n * 800 + o] = s;
    }
}

// conv1 MFMA (swapped): imgp -> h1e/h1o. grid (64,64), block 256.
// D after swap: lane (ml,kg) holds pixel 16t+ml, co = cohalf*16 + kg*4 + r.
__global__ __launch_bounds__(256, 4) void conv1_mfma(const unsigned short* __restrict__ imgp,
                                                     const short* __restrict__ B1,
                                                     const float* __restrict__ bias,
                                                     unsigned short* __restrict__ h1e,
                                                     unsigned short* __restrict__ h1o) {
    const int tid = threadIdx.x;
    const int lane = tid & 63;
    const int w = tid >> 6;
    const int n = blockIdx.y;
    const int cohalf = w & 1;
    const int oy = blockIdx.x * 2 + (w >> 1);     // 0..127
    const int ml = lane & 15;
    const int kg = lane >> 4;

    bf16x8 bfrag[5];
    #pragma unroll
    for (int kh = 0; kh < 5; ++kh)
        bfrag[kh] = *(const bf16x8*)(B1 + ((kh * 32 + cohalf * 16 + ml) * 32 + kg * 8));

    f32x4 acc[8];
    #pragma unroll
    for (int t = 0; t < 8; ++t) acc[t] = (f32x4){0.f, 0.f, 0.f, 0.f};

    #pragma unroll
    for (int kh = 0; kh < 5; ++kh) {
        const unsigned short* rowbase = imgp + (size_t)(n * 260 + 2 * oy + kh) * 1056;
        bf16x8 af[8];
        #pragma unroll
        for (int t = 0; t < 8; ++t) {
            const int px0 = 2 * (16 * t + ml) + 2 * kg;
            af[t] = *(const bf16x8*)(rowbase + px0 * 4);
        }
        __builtin_amdgcn_sched_barrier(0);
        #pragma unroll
        for (int t = 0; t < 8; ++t)   // SWAPPED: A=weights, B=pixels
            acc[t] = __builtin_amdgcn_mfma_f32_16x16x32_bf16(bfrag[kh], af[t], acc[t], 0, 0, 0);
    }
    const f32x4 b4 = *(const f32x4*)(bias + cohalf * 16 + kg * 4);
    const int cobase = cohalf * 16 + kg * 4;
    const size_t rowoff = ((size_t)(n * 132) + oy + 2) * 2112;   // 2112 = 66*32
    #pragma unroll
    for (int t = 0; t < 8; ++t) {
        const int px = 16 * t + ml;
        uint2 uv;
        uv.x = pk2(fmaxf(acc[t][0] + b4[0], 0.f), fmaxf(acc[t][1] + b4[1], 0.f));
        uv.y = pk2(fmaxf(acc[t][2] + b4[2], 0.f), fmaxf(acc[t][3] + b4[3], 0.f));
        if (ml & 1) *(uint2*)(h1o + rowoff + (size_t)((px + 1) >> 1) * 32 + cobase) = uv;
        else        *(uint2*)(h1e + rowoff + (size_t)((px + 2) >> 1) * 32 + cobase) = uv;
    }
}

// conv2 via 32x32x16 MFMA (swapped), parity-split stride-1 A, B per-kh LDS,
// dual acc chains. Lane holds pixel x0+ml, co(r) = (r&3)+8*(r>>2)+4*kgrp.
__global__ __launch_bounds__(256, 4) void conv2_mfma32(const unsigned short* __restrict__ h1e,
                                                       const unsigned short* __restrict__ h1o,
                                                       const unsigned int* __restrict__ B,
                                                       const float* __restrict__ bias,
                                                       unsigned short* __restrict__ h2p) {
    __shared__ unsigned int Bs[5 * 32 * 20];       // 5 taps x 32 co x 40 bf16 = 12800 B
    const int tid = threadIdx.x;
    const int lane = tid & 63;
    const int w = tid >> 6;
    const int n = blockIdx.y;
    const int oy = blockIdx.x * 2 + (w >> 1);      // 0..63
    const int x0 = (w & 1) * 32;
    const int ml = lane & 31;                      // weight row (co) AND pixel col
    const int kgrp = lane >> 5;                    // 0/1

    f32x16 accA, accB;
    #pragma unroll
    for (int r = 0; r < 16; ++r) { accA[r] = 0.f; accB[r] = 0.f; }

    const unsigned short* bbase = (const unsigned short*)Bs + ml * 40 + kgrp * 8;
    const int qbase = (x0 + ml) * 32 + kgrp * 8;   // stride-1 pixel index in E/O

    for (int kh = 0; kh < 5; ++kh) {
        if (kh) __syncthreads();
        const unsigned int* src = B + kh * 2560;
        #pragma unroll
        for (int i = tid; i < 2560; i += 256) {
            int row = i >> 4, p = i & 15;
            Bs[row * 20 + p] = src[i];
        }
        __syncthreads();

        const size_t rowoff = ((size_t)(n * 132) + 2 * oy + kh) * 2112;
        const unsigned short* re = h1e + rowoff + qbase;
        const unsigned short* ro = h1o + rowoff + qbase;
        bf16x8 ae[6], ao[4];
        #pragma unroll
        for (int j = 0; j < 3; ++j) {
            ae[2 * j]     = *(const bf16x8*)(re + j * 32);
            ae[2 * j + 1] = *(const bf16x8*)(re + j * 32 + 16);
        }
        #pragma unroll
        for (int j = 0; j < 2; ++j) {
            ao[2 * j]     = *(const bf16x8*)(ro + j * 32);
            ao[2 * j + 1] = *(const bf16x8*)(ro + j * 32 + 16);
        }
        __builtin_amdgcn_sched_barrier(0);   // global A-loads stay batched above
        #pragma unroll
        for (int j = 0; j < 3; ++j) {        // kw = 2j, chain A (SWAPPED args)
            const bf16x8 b0 = *(const bf16x8*)(bbase + (2 * j) * 1280);
            const bf16x8 b1 = *(const bf16x8*)(bbase + (2 * j) * 1280 + 16);
            accA = __builtin_amdgcn_mfma_f32_32x32x16_bf16(b0, ae[2 * j], accA, 0, 0, 0);
            accA = __builtin_amdgcn_mfma_f32_32x32x16_bf16(b1, ae[2 * j + 1], accA, 0, 0, 0);
        }
        #pragma unroll
        for (int j = 0; j < 2; ++j) {        // kw = 2j+1, chain B
            const bf16x8 b0 = *(const bf16x8*)(bbase + (2 * j + 1) * 1280);
            const bf16x8 b1 = *(const bf16x8*)(bbase + (2 * j + 1) * 1280 + 16);
            accB = __builtin_amdgcn_mfma_f32_32x32x16_bf16(b0, ao[2 * j], accB, 0, 0, 0);
            accB = __builtin_amdgcn_mfma_f32_32x32x16_bf16(b1, ao[2 * j + 1], accB, 0, 0, 0);
        }
    }
    const int px = x0 + ml;
    unsigned short* dst = h2p + ((size_t)(n * 68 + oy + 2) * 68 + px + 2) * 32;
    #pragma unroll
    for (int g = 0; g < 4; ++g) {            // co group: 8g + 4kgrp + {0..3}
        const f32x4 b4 = *(const f32x4*)(bias + 8 * g + 4 * kgrp);
        float a0 = accA[4 * g + 0] + accB[4 * g + 0] + b4[0];
        float a1 = accA[4 * g + 1] + accB[4 * g + 1] + b4[1];
        float a2 = accA[4 * g + 2] + accB[4 * g + 2] + b4[2];
        float a3 = accA[4 * g + 3] + accB[4 * g + 3] + b4[3];
        uint2 uv;
        uv.x = pk2(fmaxf(a0, 0.f), fmaxf(a1, 0.f));
        uv.y = pk2(fmaxf(a2, 0.f), fmaxf(a3, 0.f));
        *(uint2*)(dst + 8 * g + 4 * kgrp) = uv;
    }
}

// xconv: depthwise per-sample k5; LDS input tile + LDS-transpose epilogue.
__global__ __launch_bounds__(256) void xconv_kernel(const unsigned short* __restrict__ h2p,
                                                    const float* __restrict__ ker,
                                                    unsigned short* __restrict__ sap) {
    __shared__ __align__(16) unsigned short tile[12 * 68 * 32];   // 52 KB
    const int tid = threadIdx.x;
    const int n = blockIdx.x;
    const int rb = blockIdx.y;
    const unsigned short* src = h2p + (size_t)(n * 68 + rb * 8) * (68 * 32);
    for (int i = tid; i < 3264; i += 256)
        *(uint4*)(tile + i * 8) = *(const uint4*)(src + i * 8);
    const int ci = tid & 31, xg = tid >> 5;
    const float* kp = ker + (size_t)(n * 32 + ci) * 25;
    float k[25];
    #pragma unroll
    for (int t = 0; t < 25; ++t) k[t] = kp[t];
    __syncthreads();

    float acc[8][8];
    #pragma unroll
    for (int r = 0; r < 8; ++r)
        #pragma unroll
        for (int j = 0; j < 8; ++j) acc[r][j] = 0.f;

    #pragma unroll
    for (int ir = 0; ir < 12; ++ir) {
        float v[12];
        #pragma unroll
        for (int t = 0; t < 12; ++t)
            v[t] = bf2f(tile[(ir * 68 + xg * 8 + t) * 32 + ci]);
        #pragma unroll
        for (int kh = 0; kh < 5; ++kh) {
            const int r = ir - kh;
            if (r >= 0 && r < 8) {
                #pragma unroll
                for (int j = 0; j < 8; ++j) {
                    float s = acc[r][j];
                    #pragma unroll
                    for (int kw = 0; kw < 5; ++kw) s += k[kh * 5 + kw] * v[j + kw];
                    acc[r][j] = s;
                }
            }
        }
    }
    // transpose epilogue: repack into tile (input dead), then coalesced copy.
    __syncthreads();
    #pragma unroll
    for (int r = 0; r < 8; ++r)
        #pragma unroll
        for (int j = 0; j < 8; ++j)
            tile[(r * 64 + xg * 8 + j) * 32 + ci] = f2bf(acc[r][j]);
    __syncthreads();
    #pragma unroll
    for (int r = 0; r < 8; ++r) {
        uint4 v = *(const uint4*)(tile + (size_t)r * 2048 + tid * 8);
        *(uint4*)(sap + ((size_t)(n * 66 + rb * 8 + r + 1) * 66 + 1) * 32 + tid * 8) = v;
    }
}

// mp1 via 32x32x16 MFMA (swapped); all 9 taps staged once in LDS; dual chains.
__global__ __launch_bounds__(256, 4) void mp1_mfma32(const unsigned short* __restrict__ sap,
                                                     const unsigned int* __restrict__ B,
                                                     const float* __restrict__ bias,
                                                     unsigned short* __restrict__ fp) {
    __shared__ unsigned int Bs[9 * 32 * 20];       // 23040 B
    const int tid = threadIdx.x;
    #pragma unroll
    for (int i = tid; i < 4608; i += 256) {
        int row = i >> 4, p = i & 15;
        Bs[row * 20 + p] = B[i];
    }
    __syncthreads();

    const int lane = tid & 63;
    const int w = tid >> 6;
    const int n = blockIdx.y;
    const int oy = blockIdx.x * 2 + (w >> 1);      // 0..63
    const int x0 = (w & 1) * 32;
    const int ml = lane & 31;
    const int kgrp = lane >> 5;

    f32x16 accA, accB;
    #pragma unroll
    for (int r = 0; r < 16; ++r) { accA[r] = 0.f; accB[r] = 0.f; }

    const unsigned short* bbase = (const unsigned short*)Bs + ml * 40 + kgrp * 8;
    const int px0 = x0 + ml;

    #pragma unroll
    for (int kh = 0; kh < 3; ++kh) {
        const unsigned short* rowbase = sap + (size_t)(n * 66 + oy + kh) * 2112 + kgrp * 8;
        bf16x8 a[6];
        #pragma unroll
        for (int kw = 0; kw < 3; ++kw) {
            a[2 * kw]     = *(const bf16x8*)(rowbase + (px0 + kw) * 32);
            a[2 * kw + 1] = *(const bf16x8*)(rowbase + (px0 + kw) * 32 + 16);
        }
        __builtin_amdgcn_sched_barrier(0);
        #pragma unroll
        for (int kw = 0; kw < 3; ++kw) {
            const int tap = kh * 3 + kw;
            const bf16x8 b0 = *(const bf16x8*)(bbase + tap * 1280);
            const bf16x8 b1 = *(const bf16x8*)(bbase + tap * 1280 + 16);
            if (tap & 1) {
                accB = __builtin_amdgcn_mfma_f32_32x32x16_bf16(b0, a[2 * kw], accB, 0, 0, 0);
                accB = __builtin_amdgcn_mfma_f32_32x32x16_bf16(b1, a[2 * kw + 1], accB, 0, 0, 0);
            } else {
                accA = __builtin_amdgcn_mfma_f32_32x32x16_bf16(b0, a[2 * kw], accA, 0, 0, 0);
                accA = __builtin_amdgcn_mfma_f32_32x32x16_bf16(b1, a[2 * kw + 1], accA, 0, 0, 0);
            }
        }
    }
    const int px = x0 + ml;
    unsigned short* dst = fp + ((size_t)(n * 66 + oy + 1) * 66 + px + 1) * 32;
    #pragma unroll
    for (int g = 0; g < 4; ++g) {
        const f32x4 b4 = *(const f32x4*)(bias + 8 * g + 4 * kgrp);
        float a0 = accA[4 * g + 0] + accB[4 * g + 0] + b4[0];
        float a1 = accA[4 * g + 1] + accB[4 * g + 1] + b4[1];
        float a2 = accA[4 * g + 2] + accB[4 * g + 2] + b4[2];
        float a3 = accA[4 * g + 3] + accB[4 * g + 3] + b4[3];
        uint2 uv;
        uv.x = pk2(fmaxf(a0, 0.f), fmaxf(a1, 0.f));
        uv.y = pk2(fmaxf(a2, 0.f), fmaxf(a3, 0.f));
        *(uint2*)(dst + 8 * g + 4 * kgrp) = uv;
    }
}

// mp2 MFMA: fpb -> flow f32 NCHW. B 16 cols (co 0/1 real). grid (16,64).
__global__ __launch_bounds__(256, 4) void mp2_mfma(const unsigned short* __restrict__ fpb,
                                                   const short* __restrict__ B,
                                                   const float* __restrict__ bias,
                                                   float* __restrict__ out) {
    const int tid = threadIdx.x;
    const int lane = tid & 63;
    const int w = tid >> 6;
    const int n = blockIdx.y;
    const int oy = blockIdx.x * 4 + w;    // 0..63
    const int ml = lane & 15;
    const int kg = lane >> 4;

    bf16x8 bfrag[9];
    #pragma unroll
    for (int t = 0; t < 9; ++t)
        bfrag[t] = *(const bf16x8*)(B + ((t * 16 + ml) * 32 + kg * 8));
    const float bia = (ml < 2) ? bias[ml] : 0.f;

    f32x4 acc[4];
    #pragma unroll
    for (int t = 0; t < 4; ++t) acc[t] = (f32x4){bia, bia, bia, bia};

    #pragma unroll
    for (int kh = 0; kh < 3; ++kh) {
        const unsigned short* rowbase = fpb + (size_t)(n * 66 + oy + kh) * (66 * 32);
        bf16x8 af[12];
        #pragma unroll
        for (int kw = 0; kw < 3; ++kw)
            #pragma unroll
            for (int t = 0; t < 4; ++t)
                af[kw * 4 + t] = *(const bf16x8*)(rowbase + (16 * t + ml + kw) * 32 + kg * 8);
        __builtin_amdgcn_sched_barrier(0);
        #pragma unroll
        for (int kw = 0; kw < 3; ++kw)
            #pragma unroll
            for (int t = 0; t < 4; ++t)
                acc[t] = __builtin_amdgcn_mfma_f32_16x16x32_bf16(af[kw * 4 + t], bfrag[kh * 3 + kw], acc[t], 0, 0, 0);
    }
    if (ml < 2) {
        #pragma unroll
        for (int t = 0; t < 4; ++t) {
            #pragma unroll
            for (int r = 0; r < 4; ++r) {
                const int px = 16 * t + kg * 4 + r;
                out[(size_t)n * 8192 + (size_t)ml * 4096 + (size_t)oy * 64 + px] = acc[t][r];
            }
        }
    }
}

extern "C" void kernel_launch(void* const* d_in, const int* in_sizes, int n_in,
                              void* d_out, int out_size, void* d_ws, size_t ws_size,
                              hipStream_t stream) {
    (void)in_sizes; (void)n_in; (void)out_size; (void)ws_size;
    const float* images  = (const float*)d_in[0];
    const float* actions = (const float*)d_in[1];
    const float* pe_w1   = (const float*)d_in[2];
    const float* pe_b1   = (const float*)d_in[3];
    const float* pe_w2   = (const float*)d_in[4];
    const float* pe_b2   = (const float*)d_in[5];
    const float* ae_w1   = (const float*)d_in[6];
    const float* ae_b1   = (const float*)d_in[7];
    const float* ae_w2   = (const float*)d_in[8];
    const float* ae_b2   = (const float*)d_in[9];
    const float* mp_w1   = (const float*)d_in[10];
    const float* mp_b1   = (const float*)d_in[11];
    const float* mp_w2   = (const float*)d_in[12];
    const float* mp_b2   = (const float*)d_in[13];
    float* out = (float*)d_out;

    char* ws = (char*)d_ws;
    float* a_ker          = (float*)(ws + 0);               // 204800
    unsigned short* B1    = (unsigned short*)(ws + 204800); // 10240
    unsigned short* B2    = (unsigned short*)(ws + 215040); // 51200
    unsigned short* Bm1   = (unsigned short*)(ws + 266240); // 18432
    unsigned short* Bm2   = (unsigned short*)(ws + 284672); // 9216
    unsigned short* h1e   = (unsigned short*)(ws + 524288);    // 35,684,352
    unsigned short* h1o   = (unsigned short*)(ws + 36208640);  // 35,684,352 -> 71,892,992
    unsigned short* imgp  = (unsigned short*)(ws + 71892992);  // 35,143,680 (dead after conv1)
    unsigned short* h2p   = (unsigned short*)(ws + 71892992);  // 18,939,904 (aliases imgp)
    unsigned short* sap   = (unsigned short*)(ws + 90832896);  // 17,842,176 (aliases imgp tail)
    unsigned short* fpb   = (unsigned short*)(ws + 108675072); // 17,842,176 -> 126,517,248

    repack_all<<<174, 256, 0, stream>>>(pe_w1, pe_w2, mp_w1, mp_w2, B1, B2, Bm1, Bm2);
    mlp_kernel<<<dim3(4, 64), 256, 0, stream>>>(actions, ae_w1, ae_b1, ae_w2, ae_b2, a_ker);
    zero_border_eo<<<dim3(64 * 132, 2), 64, 0, stream>>>((unsigned int*)h1e, (unsigned int*)h1o);
    zero_border2<<<dim3(64 * 66, 1), 64, 0, stream>>>((unsigned int*)fpb, 66, 1,
                                                      (unsigned int*)fpb, 66, 1);

    pad_img_kernel<<<64 * 260, 256, 0, stream>>>(images, imgp);
    conv1_mfma<<<dim3(64, 64), 256, 0, stream>>>(imgp, (const short*)B1, pe_b1, h1e, h1o);

    // imgp dead from here; its region is reused by h2p/sap
    zero_border2<<<dim3(64 * 68, 2), 64, 0, stream>>>((unsigned int*)h2p, 68, 2,
                                                      (unsigned int*)sap, 66, 1);

    conv2_mfma32<<<dim3(32, 64), 256, 0, stream>>>(h1e, h1o, (const unsigned int*)B2, pe_b2, h2p);
    xconv_kernel<<<dim3(64, 8), 256, 0, stream>>>(h2p, a_ker, sap);
    mp1_mfma32<<<dim3(32, 64), 256, 0, stream>>>(sap, (const unsigned int*)Bm1, mp_b1, fpb);
    mp2_mfma<<<dim3(16, 64), 256, 0, stream>>>(fpb, (const short*)Bm2, mp_b2, out);
}